// Round 1
// baseline (97666.156 us; speedup 1.0000x reference)
//
#include <hip/hip_runtime.h>
#include <math.h>

#define NB 512
#define LL 16
#define WD 256
#define G3 768

// ws layout (floats)
#define OFF_WHLT 0         // [k][w] 256x256 : Wh_l^T
#define OFF_WHUT 65536     // [k][w] 256x256 : Wh_u^T
#define OFF_WHHT 131072    // [k][r] 256x768 : W_hh^T
#define OFF_A    327680    // 768 : W_ih[:,0]-W_ih[:,1]
#define OFF_BI   328448    // 768 : W_ih[:,1]+b_ih

__global__ __launch_bounds__(256)
void gru2d_prep(const float* __restrict__ W_ih,
                const float* __restrict__ W_hh,
                const float* __restrict__ b_ih,
                const float* __restrict__ W_hcat,
                float* __restrict__ ws) {
    int e = blockIdx.x * 256 + threadIdx.x;
    if (e < WD * G3) {
        int k = e / G3, r = e - k * G3;
        ws[OFF_WHHT + e] = W_hh[r * WD + k];
    }
    if (e < WD * WD) {
        int k = e >> 8, w = e & 255;
        ws[OFF_WHLT + e] = W_hcat[w * 512 + k];
        ws[OFF_WHUT + e] = W_hcat[w * 512 + WD + k];
    }
    if (e < G3) {
        float w0 = W_ih[2 * e], w1 = W_ih[2 * e + 1];
        ws[OFF_A + e] = w0 - w1;
        ws[OFF_BI + e] = w1 + b_ih[e];
    }
}

__device__ __forceinline__ float fsig(float v) {
    return 1.f / (1.f + __expf(-v));
}
__device__ __forceinline__ float ftanh_(float v) {
    v = fminf(fmaxf(v, -15.f), 15.f);
    float e = __expf(-2.f * v);
    return (1.f - e) / (1.f + e);
}

// One block = 2 batch elements, 256 threads (thread w owns hidden index w).
// All 256 steps sequential inside the kernel; h state lives in LDS.
__global__ __launch_bounds__(256)
void gru2d_main(const float* __restrict__ x,
                const float* __restrict__ b_hh,
                const float* __restrict__ W_fc,
                const float* __restrict__ b_fc,
                const float* __restrict__ W_xcat,
                const float* __restrict__ ws,
                float* __restrict__ out) {
    __shared__ float sh_hprev[2][LL][WD];   // previous row h, natural col order
    __shared__ float sh_h[2][WD];           // h_left (== h_next after update)
    __shared__ float sh_hint[2][WD];
    __shared__ float sh_A[G3];
    __shared__ float sh_Bi[G3];
    __shared__ float sh_bhh[G3];
    __shared__ float sh_wfc[2][WD];
    __shared__ float sh_x[2][256];
    __shared__ float sh_logit[2][2];

    const int tid = threadIdx.x;
    const int b0 = blockIdx.x * 2;

    for (int idx = tid; idx < G3; idx += 256) {
        sh_A[idx]   = ws[OFF_A + idx];
        sh_Bi[idx]  = ws[OFF_BI + idx];
        sh_bhh[idx] = b_hh[idx];
    }
    sh_wfc[0][tid] = W_fc[tid];
    sh_wfc[1][tid] = W_fc[WD + tid];
    sh_x[0][tid] = x[b0 * 256 + tid];
    sh_x[1][tid] = x[(b0 + 1) * 256 + tid];
    {
        float* hp = (float*)sh_hprev;
        for (int idx = tid; idx < 2 * LL * WD; idx += 256) hp[idx] = 0.f;
    }

    const float xc0 = W_xcat[0], xc1 = W_xcat[1];
    const float bf0 = b_fc[0], bf1 = b_fc[1];

    const float* __restrict__ wl = ws + OFF_WHLT + tid;  // Wh_l[tid][k] at wl[k*WD]
    const float* __restrict__ wu = ws + OFF_WHUT + tid;
    const float* __restrict__ wh = ws + OFF_WHHT + tid;  // W_hh[tid][k] at wh[k*G3]

    float lp_acc = 0.f;  // used by tid 0,1 only

    __syncthreads();

    for (int i = 0; i < LL; ++i) {
        sh_h[0][tid] = 0.f;
        sh_h[1][tid] = 0.f;
        const int odd = i & 1;
        const int dir = odd ? -1 : 1;
        const int c0 = odd ? (LL - 1) : 0;
        __syncthreads();

        for (int t = 0; t < LL; ++t) {
            const int c = c0 + dir * t;
            const float* __restrict__ hup0 = sh_hprev[0][c];
            const float* __restrict__ hup1 = sh_hprev[1][c];

            // ---- h_int = Wh_l @ h_left + Wh_u @ h_up ----
            float a0l = 0.f, a0u = 0.f, a1l = 0.f, a1u = 0.f;
            #pragma unroll
            for (int kk = 0; kk < WD; kk += 16) {
                float wlv[16], wuv[16];
                #pragma unroll
                for (int u = 0; u < 16; ++u) {
                    wlv[u] = wl[(kk + u) * WD];
                    wuv[u] = wu[(kk + u) * WD];
                }
                #pragma unroll
                for (int u = 0; u < 16; ++u) {
                    a0l += wlv[u] * sh_h[0][kk + u];
                    a1l += wlv[u] * sh_h[1][kk + u];
                    a0u += wuv[u] * hup0[kk + u];
                    a1u += wuv[u] * hup1[kk + u];
                }
            }
            const float hi0 = a0l + a0u;
            const float hi1 = a1l + a1u;
            sh_hint[0][tid] = hi0;
            sh_hint[1][tid] = hi1;
            __syncthreads();  // B1

            // ---- gh = W_hh @ h_int (rows tid, 256+tid, 512+tid) ----
            float gr0 = 0.f, gz0 = 0.f, gn0 = 0.f;
            float gr1 = 0.f, gz1 = 0.f, gn1 = 0.f;
            #pragma unroll
            for (int kk = 0; kk < WD; kk += 8) {
                float wr[8], wzv[8], wn[8];
                #pragma unroll
                for (int u = 0; u < 8; ++u) {
                    wr[u]  = wh[(kk + u) * G3];
                    wzv[u] = wh[(kk + u) * G3 + WD];
                    wn[u]  = wh[(kk + u) * G3 + 2 * WD];
                }
                #pragma unroll
                for (int u = 0; u < 8; ++u) {
                    float h0 = sh_hint[0][kk + u];
                    float h1 = sh_hint[1][kk + u];
                    gr0 += wr[u] * h0;  gr1 += wr[u] * h1;
                    gz0 += wzv[u] * h0; gz1 += wzv[u] * h1;
                    gn0 += wn[u] * h0;  gn1 += wn[u] * h1;
                }
            }

            // ---- gates + h_next ----
            float hn_[2];
            #pragma unroll
            for (int b = 0; b < 2; ++b) {
                float xl = (t == 0) ? 0.f : sh_x[b][i * LL + (c - dir)];
                float xu = (i == 0) ? 0.f : sh_x[b][(i - 1) * LL + c];
                float pu = (xl * xc0 + xu * xc1 + 1.f) * 0.5f;
                float gr = b ? gr1 : gr0;
                float gz = b ? gz1 : gz0;
                float gn = b ? gn1 : gn0;
                float hi = b ? hi1 : hi0;
                float r = fsig(sh_A[tid] * pu + sh_Bi[tid] + gr + sh_bhh[tid]);
                float z = fsig(sh_A[WD + tid] * pu + sh_Bi[WD + tid] + gz + sh_bhh[WD + tid]);
                float n = ftanh_(sh_A[2 * WD + tid] * pu + sh_Bi[2 * WD + tid]
                                 + r * (gn + sh_bhh[2 * WD + tid]));
                hn_[b] = (1.f - z) * n + z * hi;
            }
            sh_h[0][tid] = hn_[0];
            sh_h[1][tid] = hn_[1];
            sh_hprev[0][c][tid] = hn_[0];
            sh_hprev[1][c][tid] = hn_[1];
            __syncthreads();  // B2

            // ---- fc: wave wv -> (batch, logit) dot of length 256 ----
            {
                const int wv = tid >> 6, lane = tid & 63;
                const int bb = wv >> 1, lg = wv & 1;
                const float* hv = sh_h[bb];
                const float* wf = sh_wfc[lg];
                float s = 0.f;
                #pragma unroll
                for (int q = 0; q < 4; ++q) s += hv[lane * 4 + q] * wf[lane * 4 + q];
                #pragma unroll
                for (int o = 32; o > 0; o >>= 1) s += __shfl_down(s, o);
                if (lane == 0) sh_logit[bb][lg] = s;
            }
            __syncthreads();  // B3

            if (tid < 2) {
                float l0 = sh_logit[tid][0] + bf0;
                float l1 = sh_logit[tid][1] + bf1;
                float mx = fmaxf(l0, l1);
                float lse = mx + logf(__expf(l0 - mx) + __expf(l1 - mx));
                float xcur = sh_x[tid][i * LL + c];
                float m = (1.f + xcur) * 0.5f;
                float lp = (l0 - lse) * m + (l1 - lse) * (1.f - m);
                if (i == 0 && c == 0) lp = 1.f - m;  // lp[:,0,0] override
                lp_acc += lp;
            }
        }
    }
    if (tid < 2) out[b0 + tid] = lp_acc;
}

extern "C" void kernel_launch(void* const* d_in, const int* in_sizes, int n_in,
                              void* d_out, int out_size, void* d_ws, size_t ws_size,
                              hipStream_t stream) {
    const float* x      = (const float*)d_in[0];
    const float* W_ih   = (const float*)d_in[1];
    const float* W_hh   = (const float*)d_in[2];
    const float* b_ih   = (const float*)d_in[3];
    const float* b_hh   = (const float*)d_in[4];
    const float* W_fc   = (const float*)d_in[5];
    const float* b_fc   = (const float*)d_in[6];
    const float* W_hcat = (const float*)d_in[7];
    const float* W_xcat = (const float*)d_in[8];
    float* out = (float*)d_out;
    float* ws  = (float*)d_ws;

    gru2d_prep<<<768, 256, 0, stream>>>(W_ih, W_hh, b_ih, W_hcat, ws);
    gru2d_main<<<NB / 2, 256, 0, stream>>>(x, b_hh, W_fc, b_fc, W_xcat, ws, out);
}

// Round 2
// 16265.331 us; speedup vs baseline: 6.0046x; 6.0046x over previous
//
#include <hip/hip_runtime.h>
#include <math.h>

#define LL 16
#define WD 256
#define G3 768
#define NA 131072            // A-weights: [Wh_l | Wh_u] 256x512
#define NBW 196608           // B-weights: W_hh 768x256
#define OFF_GA (NA + NBW)    // 327680: 768 : W_ih[:,0]-W_ih[:,1]
#define OFF_GBI (OFF_GA + G3)// 328448: 768 : W_ih[:,1]+b_ih

// Pre-shuffle weights so main kernel's per-thread register loads are coalesced.
// Thread t (w = t&255, ch = t>>8) owns:
//   A: concat-k range [ch*128, ch*128+128) of row w of [Wh_l|Wh_u] (= W_hcat row w)
//      stored wsA[(jq*1024 + t)*4 + jr] = W_hcat[w*512 + ch*128 + jq*4 + jr]
//   B: gate rows w, w+256, w+512 of W_hh, k range [ch*64, ch*64+64)
//      e = g*64 + j; wsB[(eq*1024 + t)*4 + er] = W_hh[(w+256g)*256 + ch*64 + j]
__global__ __launch_bounds__(256)
void gru2d_prep(const float* __restrict__ W_ih,
                const float* __restrict__ W_hh,
                const float* __restrict__ b_ih,
                const float* __restrict__ W_hcat,
                float* __restrict__ ws) {
    int m = blockIdx.x * 256 + threadIdx.x;
    if (m < NA) {
        int jr = m & 3, tt = (m >> 2) & 1023, jq = m >> 12;
        int w = tt & 255, cA = tt >> 8;
        ws[m] = W_hcat[w * 512 + cA * 128 + jq * 4 + jr];
    }
    if (m < NBW) {
        int er = m & 3, tt = (m >> 2) & 1023, eq = m >> 12;
        int e = eq * 4 + er, g = e >> 6, j = e & 63;
        int w = tt & 255, cB = tt >> 8;
        ws[NA + m] = W_hh[(w + (g << 8)) * WD + cB * 64 + j];
    }
    if (m < G3) {
        float w0 = W_ih[2 * m], w1 = W_ih[2 * m + 1];
        ws[OFF_GA + m] = w0 - w1;
        ws[OFF_GBI + m] = w1 + b_ih[m];
    }
}

__device__ __forceinline__ float fsig(float v) {
    return 1.f / (1.f + __expf(-v));
}
__device__ __forceinline__ float ftanh_(float v) {
    v = fminf(fmaxf(v, -15.f), 15.f);
    float e = __expf(-2.f * v);
    return (1.f - e) / (1.f + e);
}

// 1 block/CU, 1024 threads, 2 batches/block. ALL weights live in VGPRs.
__global__ __launch_bounds__(1024, 4)
void gru2d_main(const float* __restrict__ x,
                const float* __restrict__ b_hh,
                const float* __restrict__ W_fc,
                const float* __restrict__ b_fc,
                const float* __restrict__ W_xcat,
                const float* __restrict__ ws,
                float* __restrict__ out) {
    __shared__ __attribute__((aligned(16))) float sh_hprev[2][LL][WD];
    __shared__ __attribute__((aligned(16))) float sh_h[2][WD];
    __shared__ __attribute__((aligned(16))) float sh_hint[2][WD];
    __shared__ float sh_pA[8][WD];    // [cA*2+b][w]
    __shared__ float sh_pB[24][WD];   // [(cB*3+g)*2+b][w]
    __shared__ float sh_A[G3], sh_Bi[G3], sh_bhh[G3];
    __shared__ float sh_wfc[2][WD];
    __shared__ float sh_x[2][256];

    const int tid = threadIdx.x;
    const int w = tid & 255;
    const int ch = tid >> 8;          // wave-uniform chunk id
    const int b0 = blockIdx.x * 2;

    // ---- load this thread's weights into registers (coalesced float4) ----
    float wA[128];
    float wB[192];
    const float* __restrict__ wsA = ws;
    const float* __restrict__ wsB = ws + NA;
    #pragma unroll
    for (int jq = 0; jq < 32; ++jq) {
        float4 v = *(const float4*)(wsA + ((jq << 10) + tid) * 4);
        wA[jq * 4] = v.x; wA[jq * 4 + 1] = v.y; wA[jq * 4 + 2] = v.z; wA[jq * 4 + 3] = v.w;
    }
    #pragma unroll
    for (int eq = 0; eq < 48; ++eq) {
        float4 v = *(const float4*)(wsB + ((eq << 10) + tid) * 4);
        wB[eq * 4] = v.x; wB[eq * 4 + 1] = v.y; wB[eq * 4 + 2] = v.z; wB[eq * 4 + 3] = v.w;
    }

    // ---- init LDS ----
    for (int idx = tid; idx < G3; idx += 1024) {
        sh_A[idx]   = ws[OFF_GA + idx];
        sh_Bi[idx]  = ws[OFF_GBI + idx];
        sh_bhh[idx] = b_hh[idx];
    }
    if (tid < 512) {
        sh_wfc[tid >> 8][tid & 255] = W_fc[tid];
        sh_x[tid >> 8][tid & 255] = x[(b0 + (tid >> 8)) * 256 + (tid & 255)];
    }
    {
        float* hp = (float*)sh_hprev;
        for (int idx = tid; idx < 2 * LL * WD; idx += 1024) hp[idx] = 0.f;
    }
    const float xc0 = W_xcat[0], xc1 = W_xcat[1];
    const float bf0 = b_fc[0], bf1 = b_fc[1];
    float lp_acc = 0.f;
    __syncthreads();

    for (int i = 0; i < LL; ++i) {
        const int odd = i & 1;
        const int dir = odd ? -1 : 1;
        const int c0g = odd ? (LL - 1) : 0;
        for (int t = 0; t < LL; ++t) {
            const int col = c0g + dir * t;

            // ---- Phase A: hint partials. chunks 0,1 = h_left; 2,3 = h_up ----
            {
                const float* p0; const float* p1;
                bool act = true;
                if (ch < 2) {
                    act = (t != 0);      // h_left == 0 at row start
                    p0 = &sh_h[0][ch << 7];
                    p1 = &sh_h[1][ch << 7];
                } else {
                    p0 = &sh_hprev[0][col][(ch - 2) << 7];
                    p1 = &sh_hprev[1][col][(ch - 2) << 7];
                }
                float a0 = 0.f, a1 = 0.f;
                if (act) {
                    #pragma unroll
                    for (int jq = 0; jq < 32; ++jq) {
                        float4 h0 = *(const float4*)(p0 + (jq << 2));
                        float4 h1 = *(const float4*)(p1 + (jq << 2));
                        a0 += wA[jq*4]*h0.x + wA[jq*4+1]*h0.y + wA[jq*4+2]*h0.z + wA[jq*4+3]*h0.w;
                        a1 += wA[jq*4]*h1.x + wA[jq*4+1]*h1.y + wA[jq*4+2]*h1.z + wA[jq*4+3]*h1.w;
                    }
                }
                sh_pA[(ch << 1) + 0][w] = a0;
                sh_pA[(ch << 1) + 1][w] = a1;
            }
            __syncthreads();  // B1

            // ---- reduce A -> hint ----
            if (tid < 512) {
                int b = tid >> 8, ww = tid & 255;
                sh_hint[b][ww] = sh_pA[b][ww] + sh_pA[2 + b][ww]
                               + sh_pA[4 + b][ww] + sh_pA[6 + b][ww];
            }
            __syncthreads();  // B2

            // ---- Phase B: gh partials (3 gate rows per thread) ----
            {
                const float* q0 = &sh_hint[0][ch << 6];
                const float* q1 = &sh_hint[1][ch << 6];
                float r0=0.f, z0=0.f, n0=0.f, r1=0.f, z1=0.f, n1=0.f;
                #pragma unroll
                for (int eq = 0; eq < 16; ++eq) {
                    float4 h0 = *(const float4*)(q0 + (eq << 2));
                    float4 h1 = *(const float4*)(q1 + (eq << 2));
                    const int ba = eq << 2;
                    r0 += wB[ba]*h0.x + wB[ba+1]*h0.y + wB[ba+2]*h0.z + wB[ba+3]*h0.w;
                    r1 += wB[ba]*h1.x + wB[ba+1]*h1.y + wB[ba+2]*h1.z + wB[ba+3]*h1.w;
                    z0 += wB[64+ba]*h0.x + wB[64+ba+1]*h0.y + wB[64+ba+2]*h0.z + wB[64+ba+3]*h0.w;
                    z1 += wB[64+ba]*h1.x + wB[64+ba+1]*h1.y + wB[64+ba+2]*h1.z + wB[64+ba+3]*h1.w;
                    n0 += wB[128+ba]*h0.x + wB[128+ba+1]*h0.y + wB[128+ba+2]*h0.z + wB[128+ba+3]*h0.w;
                    n1 += wB[128+ba]*h1.x + wB[128+ba+1]*h1.y + wB[128+ba+2]*h1.z + wB[128+ba+3]*h1.w;
                }
                sh_pB[ch * 6 + 0][w] = r0;
                sh_pB[ch * 6 + 1][w] = r1;
                sh_pB[ch * 6 + 2][w] = z0;
                sh_pB[ch * 6 + 3][w] = z1;
                sh_pB[ch * 6 + 4][w] = n0;
                sh_pB[ch * 6 + 5][w] = n1;
            }
            __syncthreads();  // B3

            // ---- gates + h update (threads 0..255, both batches) ----
            if (tid < 256) {
                #pragma unroll
                for (int b = 0; b < 2; ++b) {
                    float gr = sh_pB[b][w]   + sh_pB[b+6][w]  + sh_pB[b+12][w] + sh_pB[b+18][w];
                    float gz = sh_pB[b+2][w] + sh_pB[b+8][w]  + sh_pB[b+14][w] + sh_pB[b+20][w];
                    float gn = sh_pB[b+4][w] + sh_pB[b+10][w] + sh_pB[b+16][w] + sh_pB[b+22][w];
                    float hi = sh_hint[b][w];
                    float xl = (t == 0) ? 0.f : sh_x[b][(i << 4) + (col - dir)];
                    float xu = (i == 0) ? 0.f : sh_x[b][((i - 1) << 4) + col];
                    float pu = (xl * xc0 + xu * xc1 + 1.f) * 0.5f;
                    float r = fsig(sh_A[w] * pu + sh_Bi[w] + gr + sh_bhh[w]);
                    float z = fsig(sh_A[256 + w] * pu + sh_Bi[256 + w] + gz + sh_bhh[256 + w]);
                    float n = ftanh_(sh_A[512 + w] * pu + sh_Bi[512 + w]
                                     + r * (gn + sh_bhh[512 + w]));
                    float hn = (1.f - z) * n + z * hi;
                    sh_h[b][w] = hn;
                    sh_hprev[b][col][w] = hn;
                }
            }
            __syncthreads();  // B4

            // ---- FC + log-softmax: wave b handles batch b, no barrier needed ----
            if (tid < 128) {
                const int b = tid >> 6, lane = tid & 63;
                float s0 = 0.f, s1 = 0.f;
                #pragma unroll
                for (int q = 0; q < 4; ++q) {
                    float hv = sh_h[b][lane * 4 + q];
                    s0 += hv * sh_wfc[0][lane * 4 + q];
                    s1 += hv * sh_wfc[1][lane * 4 + q];
                }
                #pragma unroll
                for (int o = 32; o > 0; o >>= 1) {
                    s0 += __shfl_down(s0, o);
                    s1 += __shfl_down(s1, o);
                }
                if (lane == 0) {
                    float l0 = s0 + bf0, l1 = s1 + bf1;
                    float mx = fmaxf(l0, l1);
                    float lse = mx + logf(__expf(l0 - mx) + __expf(l1 - mx));
                    float xcur = sh_x[b][(i << 4) + col];
                    float m = (1.f + xcur) * 0.5f;
                    float lp = (l0 - lse) * m + (l1 - lse) * (1.f - m);
                    if (i == 0 && col == 0) lp = 1.f - m;
                    lp_acc += lp;
                }
            }
        }
    }
    if (tid == 0)  out[b0]     = lp_acc;
    if (tid == 64) out[b0 + 1] = lp_acc;
}

extern "C" void kernel_launch(void* const* d_in, const int* in_sizes, int n_in,
                              void* d_out, int out_size, void* d_ws, size_t ws_size,
                              hipStream_t stream) {
    const float* x      = (const float*)d_in[0];
    const float* W_ih   = (const float*)d_in[1];
    const float* W_hh   = (const float*)d_in[2];
    const float* b_ih   = (const float*)d_in[3];
    const float* b_hh   = (const float*)d_in[4];
    const float* W_fc   = (const float*)d_in[5];
    const float* b_fc   = (const float*)d_in[6];
    const float* W_hcat = (const float*)d_in[7];
    const float* W_xcat = (const float*)d_in[8];
    float* out = (float*)d_out;
    float* ws  = (float*)d_ws;

    gru2d_prep<<<768, 256, 0, stream>>>(W_ih, W_hh, b_ih, W_hcat, ws);
    gru2d_main<<<256, 1024, 0, stream>>>(x, b_hh, W_fc, b_fc, W_xcat, ws, out);
}

// Round 3
// 3823.621 us; speedup vs baseline: 25.5428x; 4.2539x over previous
//
#include <hip/hip_runtime.h>
#include <math.h>

#define LL 16
#define WD 256
#define G3 768

typedef _Float16 h2v __attribute__((ext_vector_type(2)));

// ws layout in u32 units
#define OFF_A2  0        // 65536 u32  : packed [Wh_l|Wh_u] per-thread chunks
#define OFF_B2  65536    // 98304 u32  : packed W_hh per-thread chunks
#define OFF_GA  163840   // 768 f32    : W_ih[:,0]-W_ih[:,1]
#define OFF_GBI 164608   // 768 f32    : W_ih[:,1]+b_ih

__device__ __forceinline__ unsigned packh2(float a, float b) {
    h2v v;
    v.x = (_Float16)a;
    v.y = (_Float16)b;
    return __builtin_bit_cast(unsigned, v);
}

__device__ __forceinline__ float dot2f(unsigned w, unsigned h, float acc) {
#if __has_builtin(__builtin_amdgcn_fdot2)
    return __builtin_amdgcn_fdot2(__builtin_bit_cast(h2v, w),
                                  __builtin_bit_cast(h2v, h), acc, false);
#else
    h2v a = __builtin_bit_cast(h2v, w), b = __builtin_bit_cast(h2v, h);
    return acc + (float)a.x * (float)b.x + (float)a.y * (float)b.y;
#endif
}

// Thread t (w=t&255, ch=t>>8) owns:
//  A: pairs jq=0..63 of concat-k row w of [Wh_l|Wh_u]: k = ch*128 + 2*jq
//     stored wsu[(jq4*1024 + t)*4 + r], jq=jq4*4+r
//  B: gate g rows {w,w+256,w+512} of W_hh, pairs jj=0..31: k = ch*64 + 2*jj
//     e = g*32+jj; stored wsu[OFF_B2 + (e4*1024 + t)*4 + r], e=e4*4+r
__global__ __launch_bounds__(256)
void gru2d_prep(const float* __restrict__ W_ih,
                const float* __restrict__ W_hh,
                const float* __restrict__ b_ih,
                const float* __restrict__ W_hcat,
                float* __restrict__ ws) {
    unsigned* __restrict__ wsu = (unsigned*)ws;
    int m = blockIdx.x * 256 + threadIdx.x;
    if (m < 65536) {
        int r = m & 3, t = (m >> 2) & 1023, jq4 = m >> 12;
        int jq = jq4 * 4 + r, w = t & 255, ch = t >> 8;
        int base = w * 512 + ch * 128 + 2 * jq;
        wsu[OFF_A2 + m] = packh2(W_hcat[base], W_hcat[base + 1]);
    }
    if (m < 98304) {
        int r = m & 3, t = (m >> 2) & 1023, e4 = m >> 12;
        int e = e4 * 4 + r, g = e >> 5, jj = e & 31;
        int w = t & 255, ch = t >> 8;
        int base = (w + (g << 8)) * WD + ch * 64 + 2 * jj;
        wsu[OFF_B2 + m] = packh2(W_hh[base], W_hh[base + 1]);
    }
    if (m < G3) {
        float w0 = W_ih[2 * m], w1 = W_ih[2 * m + 1];
        ws[OFF_GA + m] = w0 - w1;
        ws[OFF_GBI + m] = w1 + b_ih[m];
    }
}

__device__ __forceinline__ float fsig(float v) {
    return 1.f / (1.f + __expf(-v));
}
__device__ __forceinline__ float ftanh_(float v) {
    v = fminf(fmaxf(v, -15.f), 15.f);
    float e = __expf(-2.f * v);
    return (1.f - e) / (1.f + e);
}

// 1 block/CU, 1024 threads, 2 batches/block; f16-packed weights in VGPRs.
__global__ __launch_bounds__(1024, 4)
void gru2d_main(const float* __restrict__ x,
                const float* __restrict__ b_hh,
                const float* __restrict__ W_fc,
                const float* __restrict__ b_fc,
                const float* __restrict__ W_xcat,
                const float* __restrict__ ws,
                float* __restrict__ out) {
    __shared__ __attribute__((aligned(16))) unsigned sh_hprev2[2][LL][128]; // packed h rows
    __shared__ __attribute__((aligned(16))) unsigned sh_h2[2][128];         // packed h_left
    __shared__ __attribute__((aligned(16))) unsigned sh_hint2[2][128];      // packed hint
    __shared__ float sh_h[2][WD];        // fp32 h (FC input)
    __shared__ float sh_hint[2][WD];     // fp32 hint (z-mix input)
    __shared__ float sh_pA[8][WD];       // [ch*2+b][w]
    __shared__ float sh_pB[24][WD];      // [ch*6+g*2+b][w]
    __shared__ float sh_A[G3], sh_Bi[G3], sh_bhh[G3];
    __shared__ float sh_wfc[2][WD];
    __shared__ float sh_x[2][256];

    const int tid = threadIdx.x;
    const int w = tid & 255;
    const int ch = tid >> 8;            // wave-uniform chunk id
    const int b0 = blockIdx.x * 2;

    const unsigned* __restrict__ wsu = (const unsigned*)ws;

    // ---- weights -> registers (coalesced uint4), then pin ----
    unsigned wA2[64], wB2[96];
    #pragma unroll
    for (int q = 0; q < 16; ++q) {
        uint4 v = *(const uint4*)(wsu + OFF_A2 + ((q << 10) + tid) * 4);
        wA2[4 * q] = v.x; wA2[4 * q + 1] = v.y; wA2[4 * q + 2] = v.z; wA2[4 * q + 3] = v.w;
    }
    #pragma unroll
    for (int q = 0; q < 24; ++q) {
        uint4 v = *(const uint4*)(wsu + OFF_B2 + ((q << 10) + tid) * 4);
        wB2[4 * q] = v.x; wB2[4 * q + 1] = v.y; wB2[4 * q + 2] = v.z; wB2[4 * q + 3] = v.w;
    }
    #pragma unroll
    for (int j = 0; j < 64; ++j) asm volatile("" : "+v"(wA2[j]));
    #pragma unroll
    for (int j = 0; j < 96; ++j) asm volatile("" : "+v"(wB2[j]));

    // ---- init LDS ----
    for (int idx = tid; idx < G3; idx += 1024) {
        sh_A[idx]   = ws[OFF_GA + idx];
        sh_Bi[idx]  = ws[OFF_GBI + idx];
        sh_bhh[idx] = b_hh[idx];
    }
    if (tid < 512) {
        sh_wfc[tid >> 8][tid & 255] = W_fc[tid];
        sh_x[tid >> 8][tid & 255] = x[(b0 + (tid >> 8)) * 256 + (tid & 255)];
    }
    {
        unsigned* hp = (unsigned*)sh_hprev2;
        for (int idx = tid; idx < 2 * LL * 128; idx += 1024) hp[idx] = 0u;
    }
    const float xc0 = W_xcat[0], xc1 = W_xcat[1];
    const float bf0 = b_fc[0], bf1 = b_fc[1];
    float lp_acc = 0.f;
    __syncthreads();

    for (int i = 0; i < LL; ++i) {
        if (tid < 256) sh_h2[tid >> 7][tid & 127] = 0u;   // h_left = 0 at row start
        const int odd = i & 1;
        const int dir = odd ? -1 : 1;
        const int c0g = odd ? (LL - 1) : 0;
        __syncthreads();

        for (int t = 0; t < LL; ++t) {
            const int col = c0g + dir * t;

            // ---- Phase A: hint partials (all 16 waves) ----
            {
                const unsigned* p0;
                const unsigned* p1;
                if (ch < 2) {
                    p0 = &sh_h2[0][ch << 6];
                    p1 = &sh_h2[1][ch << 6];
                } else {
                    p0 = &sh_hprev2[0][col][(ch - 2) << 6];
                    p1 = &sh_hprev2[1][col][(ch - 2) << 6];
                }
                float a0 = 0.f, a1 = 0.f, c0a = 0.f, c1a = 0.f;
                #pragma unroll
                for (int q = 0; q < 16; ++q) {
                    uint4 h0 = *(const uint4*)(p0 + 4 * q);
                    uint4 h1 = *(const uint4*)(p1 + 4 * q);
                    a0  = dot2f(wA2[4 * q],     h0.x, a0);
                    c0a = dot2f(wA2[4 * q + 1], h0.y, c0a);
                    a0  = dot2f(wA2[4 * q + 2], h0.z, a0);
                    c0a = dot2f(wA2[4 * q + 3], h0.w, c0a);
                    a1  = dot2f(wA2[4 * q],     h1.x, a1);
                    c1a = dot2f(wA2[4 * q + 1], h1.y, c1a);
                    a1  = dot2f(wA2[4 * q + 2], h1.z, a1);
                    c1a = dot2f(wA2[4 * q + 3], h1.w, c1a);
                }
                sh_pA[(ch << 1) + 0][w] = a0 + c0a;
                sh_pA[(ch << 1) + 1][w] = a1 + c1a;
            }
            __syncthreads();  // B1

            // ---- reduce A -> hint (fp32 + packed) ----
            if (tid < 256) {
                const int b = tid >> 7, m = tid & 127;
                const int w0 = 2 * m, w1 = 2 * m + 1;
                float hi0 = sh_pA[b][w0] + sh_pA[2 + b][w0] + sh_pA[4 + b][w0] + sh_pA[6 + b][w0];
                float hi1 = sh_pA[b][w1] + sh_pA[2 + b][w1] + sh_pA[4 + b][w1] + sh_pA[6 + b][w1];
                sh_hint[b][w0] = hi0;
                sh_hint[b][w1] = hi1;
                sh_hint2[b][m] = packh2(hi0, hi1);
            }
            __syncthreads();  // B2

            // ---- Phase B: gh partials (all 16 waves) ----
            {
                const unsigned* q0 = &sh_hint2[0][ch << 5];
                const unsigned* q1 = &sh_hint2[1][ch << 5];
                float r0 = 0.f, z0 = 0.f, n0 = 0.f, r1 = 0.f, z1 = 0.f, n1 = 0.f;
                #pragma unroll
                for (int qq = 0; qq < 8; ++qq) {
                    uint4 h0 = *(const uint4*)(q0 + 4 * qq);
                    uint4 h1 = *(const uint4*)(q1 + 4 * qq);
                    unsigned hh0[4] = {h0.x, h0.y, h0.z, h0.w};
                    unsigned hh1[4] = {h1.x, h1.y, h1.z, h1.w};
                    #pragma unroll
                    for (int r = 0; r < 4; ++r) {
                        const int k = 4 * qq + r;
                        r0 = dot2f(wB2[k],      hh0[r], r0);
                        z0 = dot2f(wB2[32 + k], hh0[r], z0);
                        n0 = dot2f(wB2[64 + k], hh0[r], n0);
                        r1 = dot2f(wB2[k],      hh1[r], r1);
                        z1 = dot2f(wB2[32 + k], hh1[r], z1);
                        n1 = dot2f(wB2[64 + k], hh1[r], n1);
                    }
                }
                sh_pB[ch * 6 + 0][w] = r0;
                sh_pB[ch * 6 + 1][w] = r1;
                sh_pB[ch * 6 + 2][w] = z0;
                sh_pB[ch * 6 + 3][w] = z1;
                sh_pB[ch * 6 + 4][w] = n0;
                sh_pB[ch * 6 + 5][w] = n1;
            }
            __syncthreads();  // B3

            // ---- gates + h update (threads 0..255: b = tid>>7, two w's) ----
            if (tid < 256) {
                const int b = tid >> 7, m = tid & 127;
                float xl = (t == 0) ? 0.f : sh_x[b][(i << 4) + (col - dir)];
                float xu = (i == 0) ? 0.f : sh_x[b][((i - 1) << 4) + col];
                float pu = (xl * xc0 + xu * xc1 + 1.f) * 0.5f;
                float hn2[2];
                #pragma unroll
                for (int s = 0; s < 2; ++s) {
                    const int ww = 2 * m + s;
                    float gr = sh_pB[0 + b][ww] + sh_pB[6 + b][ww] + sh_pB[12 + b][ww] + sh_pB[18 + b][ww];
                    float gz = sh_pB[2 + b][ww] + sh_pB[8 + b][ww] + sh_pB[14 + b][ww] + sh_pB[20 + b][ww];
                    float gn = sh_pB[4 + b][ww] + sh_pB[10 + b][ww] + sh_pB[16 + b][ww] + sh_pB[22 + b][ww];
                    float hi = sh_hint[b][ww];
                    float r = fsig(sh_A[ww] * pu + sh_Bi[ww] + gr + sh_bhh[ww]);
                    float z = fsig(sh_A[256 + ww] * pu + sh_Bi[256 + ww] + gz + sh_bhh[256 + ww]);
                    float n = ftanh_(sh_A[512 + ww] * pu + sh_Bi[512 + ww]
                                     + r * (gn + sh_bhh[512 + ww]));
                    float hn = (1.f - z) * n + z * hi;
                    sh_h[b][ww] = hn;
                    hn2[s] = hn;
                }
                unsigned pk = packh2(hn2[0], hn2[1]);
                sh_h2[b][m] = pk;
                sh_hprev2[b][col][m] = pk;
            }
            __syncthreads();  // B4

            // ---- FC + log-softmax (waves 0,1) ----
            if (tid < 128) {
                const int b = tid >> 6, lane = tid & 63;
                float s0 = 0.f, s1 = 0.f;
                #pragma unroll
                for (int q = 0; q < 4; ++q) {
                    float hv = sh_h[b][lane * 4 + q];
                    s0 += hv * sh_wfc[0][lane * 4 + q];
                    s1 += hv * sh_wfc[1][lane * 4 + q];
                }
                #pragma unroll
                for (int o = 32; o > 0; o >>= 1) {
                    s0 += __shfl_down(s0, o);
                    s1 += __shfl_down(s1, o);
                }
                if (lane == 0) {
                    float l0 = s0 + bf0, l1 = s1 + bf1;
                    float mx = fmaxf(l0, l1);
                    float lse = mx + logf(__expf(l0 - mx) + __expf(l1 - mx));
                    float xcur = sh_x[b][(i << 4) + col];
                    float m = (1.f + xcur) * 0.5f;
                    float lp = (l0 - lse) * m + (l1 - lse) * (1.f - m);
                    if (i == 0 && col == 0) lp = 1.f - m;
                    lp_acc += lp;
                }
            }
        }
    }
    if (tid == 0)  out[b0]     = lp_acc;
    if (tid == 64) out[b0 + 1] = lp_acc;
}

extern "C" void kernel_launch(void* const* d_in, const int* in_sizes, int n_in,
                              void* d_out, int out_size, void* d_ws, size_t ws_size,
                              hipStream_t stream) {
    const float* x      = (const float*)d_in[0];
    const float* W_ih   = (const float*)d_in[1];
    const float* W_hh   = (const float*)d_in[2];
    const float* b_ih   = (const float*)d_in[3];
    const float* b_hh   = (const float*)d_in[4];
    const float* W_fc   = (const float*)d_in[5];
    const float* b_fc   = (const float*)d_in[6];
    const float* W_hcat = (const float*)d_in[7];
    const float* W_xcat = (const float*)d_in[8];
    float* out = (float*)d_out;
    float* ws  = (float*)d_ws;

    gru2d_prep<<<384, 256, 0, stream>>>(W_ih, W_hh, b_ih, W_hcat, ws);
    gru2d_main<<<256, 1024, 0, stream>>>(x, b_hh, W_fc, b_fc, W_xcat, ws, out);
}

// Round 4
// 1094.434 us; speedup vs baseline: 89.2389x; 3.4937x over previous
//
#include <hip/hip_runtime.h>
#include <math.h>

#define LL 16
#define WD 256
#define G3 768

// ws layout (u32 units)
#define OFF_AR  0        // 36864 u32 : A f16 pairs, reg-resident part (18 uint4/thread)
#define OFF_AL  36864    // 28672 u32 : A f16 pairs, LDS-static part (14 uint4/thread)
#define OFF_B8  65536    // 49152 u32 : W_hh int8 (24 uint4/thread)
#define OFF_SR  114688   // 768 f32 : per-row scale of W_hh (max|row|/127)
#define OFF_GA  115456   // 768 f32 : W_ih[:,0]-W_ih[:,1]
#define OFF_GBI 116224   // 768 f32 : W_ih[:,1]+b_ih

typedef _Float16 h2v __attribute__((ext_vector_type(2)));

__device__ __forceinline__ unsigned packh2(float a, float b) {
    h2v v; v.x = (_Float16)a; v.y = (_Float16)b;
    return __builtin_bit_cast(unsigned, v);
}
__device__ __forceinline__ float dot2f(unsigned w, unsigned h, float acc) {
#if __has_builtin(__builtin_amdgcn_fdot2)
    return __builtin_amdgcn_fdot2(__builtin_bit_cast(h2v, w),
                                  __builtin_bit_cast(h2v, h), acc, false);
#else
    h2v a = __builtin_bit_cast(h2v, w), b = __builtin_bit_cast(h2v, h);
    return acc + (float)a.x * (float)b.x + (float)a.y * (float)b.y;
#endif
}
__device__ __forceinline__ int sdot4(unsigned a, unsigned b, int acc) {
#if __has_builtin(__builtin_amdgcn_sdot4)
    return __builtin_amdgcn_sdot4((int)a, (int)b, acc, false);
#else
    int s = acc;
    #pragma unroll
    for (int r = 0; r < 4; ++r)
        s += (int)(signed char)(a >> (8 * r)) * (int)(signed char)(b >> (8 * r));
    return s;
#endif
}
__device__ __forceinline__ unsigned short f16b(float v) {
    _Float16 h = (_Float16)v; return __builtin_bit_cast(unsigned short, h);
}
__device__ __forceinline__ float f16f(unsigned short u) {
    return (float)__builtin_bit_cast(_Float16, u);
}
__device__ __forceinline__ float fsig(float v) { return 1.f / (1.f + __expf(-v)); }
__device__ __forceinline__ float ftanh_(float v) {
    v = fminf(fmaxf(v, -15.f), 15.f);
    float e = __expf(-2.f * v);
    return (1.f - e) / (1.f + e);
}
__device__ __forceinline__ int clampi8(int q) {
    return q > 127 ? 127 : (q < -127 ? -127 : q);
}

// per-row max-abs of W_hh -> scale
__global__ __launch_bounds__(64)
void gru2d_prep1(const float* __restrict__ W_hh, float* __restrict__ ws) {
    int row = blockIdx.x, lane = threadIdx.x;
    float s = 0.f;
    for (int k = lane; k < 256; k += 64) s = fmaxf(s, fabsf(W_hh[row * 256 + k]));
    #pragma unroll
    for (int o = 32; o > 0; o >>= 1) s = fmaxf(s, __shfl_down(s, o));
    if (lane == 0) ws[OFF_SR + row] = (s > 0.f) ? s * (1.f / 127.f) : 1.f;
}

// Thread t (w=t>>1, ch=t&1) owns:
//  A: row w of [Wh_l|Wh_u], concat-k in [ch*256, ch*256+256): 128 f16-pairs (j in [0,128))
//     j<72 -> AR region, j>=72 -> AL region; layout [(group)*512 + t]*4 + r, j=group*4+r
//  B: gate rows {w,256+w,512+w} of W_hh/srow as i8, k in [ch*128, ch*128+128):
//     u32 q = gate*32 + ku32 (ku32 in [0,32), 4 i8 each); layout [(g4)*512+t]*4+r, q=g4*4+r
__global__ __launch_bounds__(256)
void gru2d_prep2(const float* __restrict__ W_ih, const float* __restrict__ W_hh,
                 const float* __restrict__ b_ih, const float* __restrict__ W_hcat,
                 float* __restrict__ ws) {
    unsigned* __restrict__ wsu = (unsigned*)ws;
    int m = blockIdx.x * 256 + threadIdx.x;
    if (m < 36864) {
        int g = m >> 11, t5 = (m >> 2) & 511, r = m & 3;
        int w = t5 >> 1, ch = t5 & 1, j = g * 4 + r;
        int base = w * 512 + ch * 256 + 2 * j;
        wsu[OFF_AR + m] = packh2(W_hcat[base], W_hcat[base + 1]);
    } else if (m < 65536) {
        int mm = m - 36864;
        int g = mm >> 11, t5 = (mm >> 2) & 511, r = mm & 3;
        int j = 72 + g * 4 + r;
        int w = t5 >> 1, ch = t5 & 1;
        int base = w * 512 + ch * 256 + 2 * j;
        wsu[OFF_AL + mm] = packh2(W_hcat[base], W_hcat[base + 1]);
    } else if (m < 114688) {
        int mm = m - 65536;
        int g4 = mm >> 11, t5 = (mm >> 2) & 511, r = mm & 3;
        int q = g4 * 4 + r;
        int w = t5 >> 1, ch = t5 & 1;
        int gate = q >> 5, ku = (q & 31) * 4;
        int row = gate * 256 + w;
        float inv = 1.f / ws[OFF_SR + row];
        int base = row * 256 + ch * 128 + ku;
        unsigned pk = 0;
        #pragma unroll
        for (int bb = 0; bb < 4; ++bb) {
            int qv = clampi8(__float2int_rn(W_hh[base + bb] * inv));
            pk |= ((unsigned)(qv & 255)) << (8 * bb);
        }
        wsu[OFF_B8 + mm] = pk;
    } else if (m < 115456) {
        int e = m - 114688;
        float w0 = W_ih[2 * e], w1 = W_ih[2 * e + 1];
        ws[OFF_GA + e] = w0 - w1;
        ws[OFF_GBI + e] = w1 + b_ih[e];
    }
}

// 512 threads (2 waves/SIMD -> 256-VGPR budget), 1 block/CU, 2 batches/block.
// A(f16): 72 u32 regs + 56 u32 LDS per thread. B(i8): 96 u32 regs. Zero per-step HBM/L2.
__global__ __launch_bounds__(512, 2)
void gru2d_main(const float* __restrict__ x, const float* __restrict__ b_hh,
                const float* __restrict__ W_fc, const float* __restrict__ b_fc,
                const float* __restrict__ W_xcat, const float* __restrict__ ws,
                float* __restrict__ out) {
    __shared__ __attribute__((aligned(16))) uint4 ldsA[14 * 512];           // 112KB
    __shared__ __attribute__((aligned(16))) unsigned short h16[2][256];      // 1KB
    __shared__ __attribute__((aligned(16))) unsigned short hp16[2][LL][256]; // 16KB
    __shared__ __attribute__((aligned(16))) float shint[2][256];             // 2KB
    __shared__ __attribute__((aligned(16))) unsigned hint8[2][64];           // 0.5KB
    __shared__ float wmax[2][8];
    __shared__ float swfc[2][256];                                           // 2KB
    __shared__ float sx[2][256];                                             // 2KB

    const int tid = threadIdx.x;
    const int w = tid >> 1, ch = tid & 1;
    const int b0 = blockIdx.x * 2;
    const unsigned* __restrict__ wsu = (const unsigned*)ws;

    // ---- persistent weights -> registers ----
    unsigned wA[72], wB[96];
    #pragma unroll
    for (int g = 0; g < 18; ++g) {
        uint4 v = ((const uint4*)(wsu + OFF_AR))[g * 512 + tid];
        wA[4 * g] = v.x; wA[4 * g + 1] = v.y; wA[4 * g + 2] = v.z; wA[4 * g + 3] = v.w;
    }
    #pragma unroll
    for (int g = 0; g < 24; ++g) {
        uint4 v = ((const uint4*)(wsu + OFF_B8))[g * 512 + tid];
        wB[4 * g] = v.x; wB[4 * g + 1] = v.y; wB[4 * g + 2] = v.z; wB[4 * g + 3] = v.w;
    }
    // A LDS-static copy
    for (int idx = tid; idx < 14 * 512; idx += 512)
        ldsA[idx] = ((const uint4*)(wsu + OFF_AL))[idx];
    // per-thread biases/scales (for row w of each gate)
    float bA[3], bBi[3], bbh[3], bsr[3];
    #pragma unroll
    for (int g = 0; g < 3; ++g) {
        bA[g]  = ws[OFF_GA + g * 256 + w];
        bBi[g] = ws[OFF_GBI + g * 256 + w];
        bbh[g] = b_hh[g * 256 + w];
        bsr[g] = ws[OFF_SR + g * 256 + w];
    }
    swfc[ch][w] = W_fc[ch * 256 + w];
    sx[ch][w]   = x[(b0 + ch) * 256 + w];
    for (int idx = tid; idx < 2 * LL * 256; idx += 512) ((unsigned short*)hp16)[idx] = 0;
    ((unsigned short*)h16)[tid] = 0;

    const float xc0 = W_xcat[0], xc1 = W_xcat[1];
    const float bf0 = b_fc[0], bf1 = b_fc[1];
    float lp_acc = 0.f;
    __syncthreads();

    for (int i = 0; i < LL; ++i) {
        // row start: h_left = 0 (barrier above/init protects FC readers of prev step)
        ((unsigned short*)h16)[tid] = 0;
        const int odd = i & 1;
        const int dir = odd ? -1 : 1;
        const int c0g = odd ? (LL - 1) : 0;
        __syncthreads();

        for (int t = 0; t < LL; ++t) {
            const int col = c0g + dir * t;
            // keep persistent weights live across the loop (defeat remat)
            #pragma unroll
            for (int g = 0; g < 18; ++g)
                asm volatile("" : "+v"(wA[4*g]), "+v"(wA[4*g+1]), "+v"(wA[4*g+2]), "+v"(wA[4*g+3]));
            #pragma unroll
            for (int g = 0; g < 24; ++g)
                asm volatile("" : "+v"(wB[4*g]), "+v"(wB[4*g+1]), "+v"(wB[4*g+2]), "+v"(wB[4*g+3]));

            // ---- Phase A: hint = [Wh_l|Wh_u] @ [h_left; h_up] (pair-split over ch) ----
            const unsigned short* hb0 = ch ? hp16[0][col] : h16[0];
            const unsigned short* hb1 = ch ? hp16[1][col] : h16[1];
            float a0 = 0.f, a1 = 0.f;
            #pragma unroll
            for (int g = 0; g < 18; ++g) {   // reg part: k-octet g
                uint4 h0 = *(const uint4*)(hb0 + 8 * g);
                uint4 h1 = *(const uint4*)(hb1 + 8 * g);
                a0 = dot2f(wA[4*g], h0.x, a0);   a0 = dot2f(wA[4*g+1], h0.y, a0);
                a0 = dot2f(wA[4*g+2], h0.z, a0); a0 = dot2f(wA[4*g+3], h0.w, a0);
                a1 = dot2f(wA[4*g], h1.x, a1);   a1 = dot2f(wA[4*g+1], h1.y, a1);
                a1 = dot2f(wA[4*g+2], h1.z, a1); a1 = dot2f(wA[4*g+3], h1.w, a1);
            }
            #pragma unroll
            for (int g = 0; g < 14; ++g) {   // LDS-static part: k-octet 18+g
                uint4 wa = ldsA[g * 512 + tid];
                uint4 h0 = *(const uint4*)(hb0 + 144 + 8 * g);
                uint4 h1 = *(const uint4*)(hb1 + 144 + 8 * g);
                a0 = dot2f(wa.x, h0.x, a0); a0 = dot2f(wa.y, h0.y, a0);
                a0 = dot2f(wa.z, h0.z, a0); a0 = dot2f(wa.w, h0.w, a0);
                a1 = dot2f(wa.x, h1.x, a1); a1 = dot2f(wa.y, h1.y, a1);
                a1 = dot2f(wa.z, h1.z, a1); a1 = dot2f(wa.w, h1.w, a1);
            }
            a0 += __shfl_xor(a0, 1);
            a1 += __shfl_xor(a1, 1);   // both lanes now hold full hint for (w), b0 & b1

            // wave-max for dynamic i8 scale of hint
            float m0 = fabsf(a0), m1 = fabsf(a1);
            #pragma unroll
            for (int o = 2; o < 64; o <<= 1) {
                m0 = fmaxf(m0, __shfl_xor(m0, o));
                m1 = fmaxf(m1, __shfl_xor(m1, o));
            }
            shint[ch][w] = ch ? a1 : a0;
            if ((tid & 63) == 0) { wmax[0][tid >> 6] = m0; wmax[1][tid >> 6] = m1; }
            __syncthreads();  // B1

            float hm0 = wmax[0][0], hm1 = wmax[1][0];
            #pragma unroll
            for (int v = 1; v < 8; ++v) { hm0 = fmaxf(hm0, wmax[0][v]); hm1 = fmaxf(hm1, wmax[1][v]); }
            const float qs0 = 127.f / fmaxf(hm0, 1e-20f), dq0 = hm0 * (1.f / 127.f);
            const float qs1 = 127.f / fmaxf(hm1, 1e-20f), dq1 = hm1 * (1.f / 127.f);
            if (tid < 128) {  // quantize+pack hint -> i8
                int b = tid >> 6, u = tid & 63;
                float qs = b ? qs1 : qs0;
                const float* sp = shint[b] + 4 * u;
                int q0 = clampi8(__float2int_rn(sp[0] * qs));
                int q1 = clampi8(__float2int_rn(sp[1] * qs));
                int q2 = clampi8(__float2int_rn(sp[2] * qs));
                int q3 = clampi8(__float2int_rn(sp[3] * qs));
                hint8[b][u] = (unsigned)(q0 & 255) | ((unsigned)(q1 & 255) << 8)
                            | ((unsigned)(q2 & 255) << 16) | ((unsigned)(q3 & 255) << 24);
            }
            __syncthreads();  // B1b

            // ---- Phase B: gh = W_hh(i8) @ hint(i8), pair-split over ch ----
            const uint4* hq0 = (const uint4*)(hint8[0] + ch * 32);
            const uint4* hq1 = (const uint4*)(hint8[1] + ch * 32);
            int ir0 = 0, iz0 = 0, in0 = 0, ir1 = 0, iz1 = 0, in1 = 0;
            #pragma unroll
            for (int gg = 0; gg < 8; ++gg) {
                uint4 u0 = hq0[gg], u1 = hq1[gg];
                const int k = gg * 4;
                ir0 = sdot4(wB[k],      u0.x, ir0); ir0 = sdot4(wB[k+1],      u0.y, ir0);
                ir0 = sdot4(wB[k+2],    u0.z, ir0); ir0 = sdot4(wB[k+3],      u0.w, ir0);
                iz0 = sdot4(wB[32+k],   u0.x, iz0); iz0 = sdot4(wB[32+k+1],   u0.y, iz0);
                iz0 = sdot4(wB[32+k+2], u0.z, iz0); iz0 = sdot4(wB[32+k+3],   u0.w, iz0);
                in0 = sdot4(wB[64+k],   u0.x, in0); in0 = sdot4(wB[64+k+1],   u0.y, in0);
                in0 = sdot4(wB[64+k+2], u0.z, in0); in0 = sdot4(wB[64+k+3],   u0.w, in0);
                ir1 = sdot4(wB[k],      u1.x, ir1); ir1 = sdot4(wB[k+1],      u1.y, ir1);
                ir1 = sdot4(wB[k+2],    u1.z, ir1); ir1 = sdot4(wB[k+3],      u1.w, ir1);
                iz1 = sdot4(wB[32+k],   u1.x, iz1); iz1 = sdot4(wB[32+k+1],   u1.y, iz1);
                iz1 = sdot4(wB[32+k+2], u1.z, iz1); iz1 = sdot4(wB[32+k+3],   u1.w, iz1);
                in1 = sdot4(wB[64+k],   u1.x, in1); in1 = sdot4(wB[64+k+1],   u1.y, in1);
                in1 = sdot4(wB[64+k+2], u1.z, in1); in1 = sdot4(wB[64+k+3],   u1.w, in1);
            }
            ir0 += __shfl_xor(ir0, 1); iz0 += __shfl_xor(iz0, 1); in0 += __shfl_xor(in0, 1);
            ir1 += __shfl_xor(ir1, 1); iz1 += __shfl_xor(iz1, 1); in1 += __shfl_xor(in1, 1);

            // ---- gates + h update: lane parity = batch ----
            {
                const float DQ = ch ? dq1 : dq0;
                const float GR = (float)(ch ? ir1 : ir0) * (DQ * bsr[0]);
                const float GZ = (float)(ch ? iz1 : iz0) * (DQ * bsr[1]);
                const float GN = (float)(ch ? in1 : in0) * (DQ * bsr[2]);
                const float HI = ch ? a1 : a0;
                float xl = (t == 0) ? 0.f : sx[ch][(i << 4) + col - dir];
                float xu = (i == 0) ? 0.f : sx[ch][((i - 1) << 4) + col];
                float pu = (xl * xc0 + xu * xc1 + 1.f) * 0.5f;
                float rr = fsig(bA[0] * pu + bBi[0] + GR + bbh[0]);
                float zz = fsig(bA[1] * pu + bBi[1] + GZ + bbh[1]);
                float nn = ftanh_(bA[2] * pu + bBi[2] + rr * (GN + bbh[2]));
                float hn = (1.f - zz) * nn + zz * HI;
                unsigned short hh = f16b(hn);
                h16[ch][w] = hh;
                hp16[ch][col][w] = hh;
            }
            __syncthreads();  // B2

            // ---- FC + log-softmax (waves 0,1; runs concurrently with next phase A) ----
            if (tid < 128) {
                const int b = tid >> 6, lane = tid & 63;
                const unsigned short* hp = h16[b] + lane * 4;
                float s0 = 0.f, s1 = 0.f;
                #pragma unroll
                for (int q = 0; q < 4; ++q) {
                    float hv = f16f(hp[q]);
                    s0 += hv * swfc[0][lane * 4 + q];
                    s1 += hv * swfc[1][lane * 4 + q];
                }
                #pragma unroll
                for (int o = 32; o > 0; o >>= 1) {
                    s0 += __shfl_down(s0, o);
                    s1 += __shfl_down(s1, o);
                }
                if (lane == 0) {
                    float l0 = s0 + bf0, l1 = s1 + bf1;
                    float mx = fmaxf(l0, l1);
                    float lse = mx + logf(__expf(l0 - mx) + __expf(l1 - mx));
                    float xcur = sx[b][(i << 4) + col];
                    float m = (1.f + xcur) * 0.5f;
                    float lp = (l0 - lse) * m + (l1 - lse) * (1.f - m);
                    if (i == 0 && col == 0) lp = 1.f - m;
                    lp_acc += lp;
                }
            }
        }
        __syncthreads();  // protect h16 zero at next row top from FC readers
    }
    if (tid == 0)  out[b0]     = lp_acc;
    if (tid == 64) out[b0 + 1] = lp_acc;
}

extern "C" void kernel_launch(void* const* d_in, const int* in_sizes, int n_in,
                              void* d_out, int out_size, void* d_ws, size_t ws_size,
                              hipStream_t stream) {
    const float* x      = (const float*)d_in[0];
    const float* W_ih   = (const float*)d_in[1];
    const float* W_hh   = (const float*)d_in[2];
    const float* b_ih   = (const float*)d_in[3];
    const float* b_hh   = (const float*)d_in[4];
    const float* W_fc   = (const float*)d_in[5];
    const float* b_fc   = (const float*)d_in[6];
    const float* W_hcat = (const float*)d_in[7];
    const float* W_xcat = (const float*)d_in[8];
    float* out = (float*)d_out;
    float* ws  = (float*)d_ws;

    gru2d_prep1<<<768, 64, 0, stream>>>(W_hh, ws);
    gru2d_prep2<<<451, 256, 0, stream>>>(W_ih, W_hh, b_ih, W_hcat, ws);
    gru2d_main<<<256, 512, 0, stream>>>(x, b_hh, W_fc, b_fc, W_xcat, ws, out);
}

// Round 5
// 974.181 us; speedup vs baseline: 100.2546x; 1.1234x over previous
//
#include <hip/hip_runtime.h>
#include <math.h>

#define LL 16
#define WD 256
#define G3 768

// ws layout (u32 units)
#define OFF_AR  0        // 36864 u32 : A f16 pairs, reg-resident part (18 uint4/thread)
#define OFF_AL  36864    // 28672 u32 : A f16 pairs, LDS-static part (14 uint4/thread)
#define OFF_B8  65536    // 49152 u32 : W_hh int8 (24 uint4/thread)
#define OFF_SR  114688   // 768 f32 : per-row scale of W_hh (max|row|/127)
#define OFF_GA  115456   // 768 f32 : W_ih[:,0]-W_ih[:,1]
#define OFF_GBI 116224   // 768 f32 : W_ih[:,1]+b_ih

typedef _Float16 h2v __attribute__((ext_vector_type(2)));

__device__ __forceinline__ unsigned packh2(float a, float b) {
    h2v v; v.x = (_Float16)a; v.y = (_Float16)b;
    return __builtin_bit_cast(unsigned, v);
}
__device__ __forceinline__ float dot2f(unsigned w, unsigned h, float acc) {
#if __has_builtin(__builtin_amdgcn_fdot2)
    return __builtin_amdgcn_fdot2(__builtin_bit_cast(h2v, w),
                                  __builtin_bit_cast(h2v, h), acc, false);
#else
    h2v a = __builtin_bit_cast(h2v, w), b = __builtin_bit_cast(h2v, h);
    return acc + (float)a.x * (float)b.x + (float)a.y * (float)b.y;
#endif
}
__device__ __forceinline__ int sdot4(unsigned a, unsigned b, int acc) {
#if __has_builtin(__builtin_amdgcn_sdot4)
    return __builtin_amdgcn_sdot4((int)a, (int)b, acc, false);
#else
    int s = acc;
    #pragma unroll
    for (int r = 0; r < 4; ++r)
        s += (int)(signed char)(a >> (8 * r)) * (int)(signed char)(b >> (8 * r));
    return s;
#endif
}
__device__ __forceinline__ unsigned short f16b(float v) {
    _Float16 h = (_Float16)v; return __builtin_bit_cast(unsigned short, h);
}
__device__ __forceinline__ float fsig(float v) { return 1.f / (1.f + __expf(-v)); }
__device__ __forceinline__ float ftanh_(float v) {
    v = fminf(fmaxf(v, -15.f), 15.f);
    float e = __expf(-2.f * v);
    return (1.f - e) / (1.f + e);
}
__device__ __forceinline__ int clampi8(int q) {
    return q > 127 ? 127 : (q < -127 ? -127 : q);
}

// per-row max-abs of W_hh -> scale
__global__ __launch_bounds__(64)
void gru2d_prep1(const float* __restrict__ W_hh, float* __restrict__ ws) {
    int row = blockIdx.x, lane = threadIdx.x;
    float s = 0.f;
    for (int k = lane; k < 256; k += 64) s = fmaxf(s, fabsf(W_hh[row * 256 + k]));
    #pragma unroll
    for (int o = 32; o > 0; o >>= 1) s = fmaxf(s, __shfl_down(s, o));
    if (lane == 0) ws[OFF_SR + row] = (s > 0.f) ? s * (1.f / 127.f) : 1.f;
}

// Thread t (w = t&255, ch = t>>8  -- ch is WAVE-UNIFORM in main) owns:
//  A: row w of [Wh_l|Wh_u], concat-k in [ch*256, ch*256+256): 128 f16-pairs j in [0,128)
//     j<72 -> AR region, j>=72 -> AL region; layout [(group)*512 + t]*4 + r, j=group*4+r
//  B: gate rows {w,256+w,512+w} of W_hh as i8, k in [ch*128, ch*128+128):
//     u32 q = gate*32 + ku32; layout [(g4)*512+t]*4+r, q=g4*4+r
__global__ __launch_bounds__(256)
void gru2d_prep2(const float* __restrict__ W_ih, const float* __restrict__ W_hh,
                 const float* __restrict__ b_ih, const float* __restrict__ W_hcat,
                 float* __restrict__ ws) {
    unsigned* __restrict__ wsu = (unsigned*)ws;
    int m = blockIdx.x * 256 + threadIdx.x;
    if (m < 36864) {
        int g = m >> 11, t5 = (m >> 2) & 511, r = m & 3;
        int w = t5 & 255, ch = t5 >> 8, j = g * 4 + r;
        int base = w * 512 + ch * 256 + 2 * j;
        wsu[OFF_AR + m] = packh2(W_hcat[base], W_hcat[base + 1]);
    } else if (m < 65536) {
        int mm = m - 36864;
        int g = mm >> 11, t5 = (mm >> 2) & 511, r = mm & 3;
        int w = t5 & 255, ch = t5 >> 8, j = 72 + g * 4 + r;
        int base = w * 512 + ch * 256 + 2 * j;
        wsu[OFF_AL + mm] = packh2(W_hcat[base], W_hcat[base + 1]);
    } else if (m < 114688) {
        int mm = m - 65536;
        int g4 = mm >> 11, t5 = (mm >> 2) & 511, r = mm & 3;
        int q = g4 * 4 + r;
        int w = t5 & 255, ch = t5 >> 8;
        int gate = q >> 5, ku = (q & 31) * 4;
        int row = gate * 256 + w;
        float inv = 1.f / ws[OFF_SR + row];
        int base = row * 256 + ch * 128 + ku;
        unsigned pk = 0;
        #pragma unroll
        for (int bb = 0; bb < 4; ++bb) {
            int qv = clampi8(__float2int_rn(W_hh[base + bb] * inv));
            pk |= ((unsigned)(qv & 255)) << (8 * bb);
        }
        wsu[OFF_B8 + mm] = pk;
    } else if (m < 115456) {
        int e = m - 114688;
        float w0 = W_ih[2 * e], w1 = W_ih[2 * e + 1];
        ws[OFF_GA + e] = w0 - w1;
        ws[OFF_GBI + e] = w1 + b_ih[e];
    }
}

// 512 threads (2 waves/SIMD), 1 block/CU, 2 batches/block.
// ch = tid>>8 is wave-uniform: ALL per-step h/hint LDS reads are uniform broadcasts.
__global__ __launch_bounds__(512, 2)
void gru2d_main(const float* __restrict__ x, const float* __restrict__ b_hh,
                const float* __restrict__ W_fc, const float* __restrict__ b_fc,
                const float* __restrict__ W_xcat, const float* __restrict__ ws,
                float* __restrict__ out) {
    __shared__ __attribute__((aligned(16))) uint4 ldsA[14 * 512];          // 112KB
    __shared__ __attribute__((aligned(16))) unsigned h2pk[2][128];          // packed f16 h_left
    __shared__ __attribute__((aligned(16))) unsigned hp2pk[2][LL][128];     // packed f16 prev-row h
    __shared__ __attribute__((aligned(16))) float pA[2][2][256];            // [ch][b][w]
    __shared__ __attribute__((aligned(16))) float pB[2][3][2][256];         // [ch][g][b][w]
    __shared__ __attribute__((aligned(16))) unsigned hint8[2][64];          // i8 hint
    __shared__ float dqs[2][4];                                             // per-64-chunk dequant
    __shared__ float fcp[2][2][4];                                          // FC partials
    __shared__ float sx[2][256];

    const int tid = threadIdx.x;
    const int w = tid & 255;
    const int ch = tid >> 8;            // wave-uniform
    const int b0 = blockIdx.x * 2;
    const unsigned* __restrict__ wsu = (const unsigned*)ws;

    // ---- persistent weights -> registers ----
    unsigned wA[72], wB[96];
    #pragma unroll
    for (int g = 0; g < 18; ++g) {
        uint4 v = ((const uint4*)(wsu + OFF_AR))[g * 512 + tid];
        wA[4 * g] = v.x; wA[4 * g + 1] = v.y; wA[4 * g + 2] = v.z; wA[4 * g + 3] = v.w;
    }
    #pragma unroll
    for (int g = 0; g < 24; ++g) {
        uint4 v = ((const uint4*)(wsu + OFF_B8))[g * 512 + tid];
        wB[4 * g] = v.x; wB[4 * g + 1] = v.y; wB[4 * g + 2] = v.z; wB[4 * g + 3] = v.w;
    }
    for (int idx = tid; idx < 14 * 512; idx += 512)
        ldsA[idx] = ((const uint4*)(wsu + OFF_AL))[idx];

    float bA[3], bBi[3], bbh[3], bsr[3];
    #pragma unroll
    for (int g = 0; g < 3; ++g) {
        bA[g]  = ws[OFF_GA + g * 256 + w];
        bBi[g] = ws[OFF_GBI + g * 256 + w];
        bbh[g] = b_hh[g * 256 + w];
        bsr[g] = ws[OFF_SR + g * 256 + w];
    }
    const float wfc0 = W_fc[w], wfc1 = W_fc[256 + w];
    sx[ch][w] = x[(b0 + ch) * 256 + w];
    {
        unsigned* hp = (unsigned*)hp2pk;
        for (int idx = tid; idx < 2 * LL * 128; idx += 512) hp[idx] = 0u;
    }
    const float xc0 = W_xcat[0], xc1 = W_xcat[1];
    const float bf0 = b_fc[0], bf1 = b_fc[1];
    float lp_acc = 0.f;
    float hi_f = 0.f;
    __syncthreads();

    for (int i = 0; i < LL; ++i) {
        const int odd = i & 1;
        const int dir = odd ? -1 : 1;
        const int c0g = odd ? (LL - 1) : 0;
        for (int t = 0; t < LL; ++t) {
            const int col = c0g + dir * t;
            const int sidx = (i << 4) + t;

            // keep persistent weights live (defeat remat)
            #pragma unroll
            for (int g = 0; g < 18; ++g)
                asm volatile("" : "+v"(wA[4*g]), "+v"(wA[4*g+1]), "+v"(wA[4*g+2]), "+v"(wA[4*g+3]));
            #pragma unroll
            for (int g = 0; g < 24; ++g)
                asm volatile("" : "+v"(wB[4*g]), "+v"(wB[4*g+1]), "+v"(wB[4*g+2]), "+v"(wB[4*g+3]));

            // ---- Phase A: hint partials; ch=0 -> h_left, ch=1 -> h_up. Uniform reads. ----
            {
                const uint4* hb0;
                const uint4* hb1;
                if (ch == 0) { hb0 = (const uint4*)h2pk[0];        hb1 = (const uint4*)h2pk[1]; }
                else         { hb0 = (const uint4*)hp2pk[0][col];  hb1 = (const uint4*)hp2pk[1][col]; }
                float a0 = 0.f, c0 = 0.f, a1 = 0.f, c1 = 0.f;
                if (!(ch == 0 && t == 0)) {
                    #pragma unroll
                    for (int g = 0; g < 18; ++g) {
                        uint4 h0 = hb0[g], h1 = hb1[g];
                        a0 = dot2f(wA[4*g],   h0.x, a0); c0 = dot2f(wA[4*g+1], h0.y, c0);
                        a0 = dot2f(wA[4*g+2], h0.z, a0); c0 = dot2f(wA[4*g+3], h0.w, c0);
                        a1 = dot2f(wA[4*g],   h1.x, a1); c1 = dot2f(wA[4*g+1], h1.y, c1);
                        a1 = dot2f(wA[4*g+2], h1.z, a1); c1 = dot2f(wA[4*g+3], h1.w, c1);
                    }
                    #pragma unroll
                    for (int g = 0; g < 14; ++g) {
                        uint4 wa = ldsA[g * 512 + tid];
                        uint4 h0 = hb0[18 + g], h1 = hb1[18 + g];
                        a0 = dot2f(wa.x, h0.x, a0); c0 = dot2f(wa.y, h0.y, c0);
                        a0 = dot2f(wa.z, h0.z, a0); c0 = dot2f(wa.w, h0.w, c0);
                        a1 = dot2f(wa.x, h1.x, a1); c1 = dot2f(wa.y, h1.y, c1);
                        a1 = dot2f(wa.z, h1.z, a1); c1 = dot2f(wa.w, h1.w, c1);
                    }
                }
                pA[ch][0][w] = a0 + c0;
                pA[ch][1][w] = a1 + c1;
            }
            __syncthreads();  // B1

            // ---- Reduce + quantize hint (thread role: (b=ch, w)); prev-step FC finalize ----
            {
                hi_f = pA[0][ch][w] + pA[1][ch][w];
                float am = fabsf(hi_f);
                #pragma unroll
                for (int o = 1; o < 64; o <<= 1) am = fmaxf(am, __shfl_xor(am, o));
                float qs = 127.f / fmaxf(am, 1e-20f);
                int q = clampi8(__float2int_rn(hi_f * qs));
                unsigned qq = (unsigned)(q & 255);
                unsigned q1 = __shfl_down(qq, 1);
                unsigned q2 = __shfl_down(qq, 2);
                unsigned q3 = __shfl_down(qq, 3);
                if ((w & 3) == 0)
                    hint8[ch][w >> 2] = qq | (q1 << 8) | (q2 << 16) | (q3 << 24);
                if ((w & 63) == 0) dqs[ch][w >> 6] = am * (1.f / 127.f);

                if (w == 0 && sidx > 0) {   // finalize FC/log-softmax of previous step
                    int ps = sidx - 1, pi2 = ps >> 4, pt2 = ps & 15;
                    int pcol = (pi2 & 1) ? (15 - pt2) : pt2;
                    float l0 = fcp[ch][0][0] + fcp[ch][0][1] + fcp[ch][0][2] + fcp[ch][0][3] + bf0;
                    float l1 = fcp[ch][1][0] + fcp[ch][1][1] + fcp[ch][1][2] + fcp[ch][1][3] + bf1;
                    float mx = fmaxf(l0, l1);
                    float lse = mx + logf(__expf(l0 - mx) + __expf(l1 - mx));
                    float xcur = sx[ch][(pi2 << 4) + pcol];
                    float mm = (1.f + xcur) * 0.5f;
                    float lp = (l0 - lse) * mm + (l1 - lse) * (1.f - mm);
                    if (pi2 == 0 && pcol == 0) lp = 1.f - mm;
                    lp_acc += lp;
                }
            }
            __syncthreads();  // B2

            // ---- Phase B: gh partials, k-half ch, per-64-chunk dequant. Uniform reads. ----
            {
                const uint4* hq0 = (const uint4*)(hint8[0] + ch * 32);
                const uint4* hq1 = (const uint4*)(hint8[1] + ch * 32);
                int ir0[2] = {0,0}, iz0[2] = {0,0}, in0[2] = {0,0};
                int ir1[2] = {0,0}, iz1[2] = {0,0}, in1[2] = {0,0};
                #pragma unroll
                for (int gg = 0; gg < 8; ++gg) {
                    const int j = gg >> 2;
                    uint4 u0 = hq0[gg], u1 = hq1[gg];
                    const int k = gg * 4;
                    ir0[j] = sdot4(wB[k],      u0.x, ir0[j]); ir0[j] = sdot4(wB[k+1],    u0.y, ir0[j]);
                    ir0[j] = sdot4(wB[k+2],    u0.z, ir0[j]); ir0[j] = sdot4(wB[k+3],    u0.w, ir0[j]);
                    iz0[j] = sdot4(wB[32+k],   u0.x, iz0[j]); iz0[j] = sdot4(wB[32+k+1], u0.y, iz0[j]);
                    iz0[j] = sdot4(wB[32+k+2], u0.z, iz0[j]); iz0[j] = sdot4(wB[32+k+3], u0.w, iz0[j]);
                    in0[j] = sdot4(wB[64+k],   u0.x, in0[j]); in0[j] = sdot4(wB[64+k+1], u0.y, in0[j]);
                    in0[j] = sdot4(wB[64+k+2], u0.z, in0[j]); in0[j] = sdot4(wB[64+k+3], u0.w, in0[j]);
                    ir1[j] = sdot4(wB[k],      u1.x, ir1[j]); ir1[j] = sdot4(wB[k+1],    u1.y, ir1[j]);
                    ir1[j] = sdot4(wB[k+2],    u1.z, ir1[j]); ir1[j] = sdot4(wB[k+3],    u1.w, ir1[j]);
                    iz1[j] = sdot4(wB[32+k],   u1.x, iz1[j]); iz1[j] = sdot4(wB[32+k+1], u1.y, iz1[j]);
                    iz1[j] = sdot4(wB[32+k+2], u1.z, iz1[j]); iz1[j] = sdot4(wB[32+k+3], u1.w, iz1[j]);
                    in1[j] = sdot4(wB[64+k],   u1.x, in1[j]); in1[j] = sdot4(wB[64+k+1], u1.y, in1[j]);
                    in1[j] = sdot4(wB[64+k+2], u1.z, in1[j]); in1[j] = sdot4(wB[64+k+3], u1.w, in1[j]);
                }
                const float d00 = dqs[0][2*ch], d01 = dqs[0][2*ch+1];
                const float d10 = dqs[1][2*ch], d11 = dqs[1][2*ch+1];
                pB[ch][0][0][w] = ((float)ir0[0]*d00 + (float)ir0[1]*d01) * bsr[0];
                pB[ch][1][0][w] = ((float)iz0[0]*d00 + (float)iz0[1]*d01) * bsr[1];
                pB[ch][2][0][w] = ((float)in0[0]*d00 + (float)in0[1]*d01) * bsr[2];
                pB[ch][0][1][w] = ((float)ir1[0]*d10 + (float)ir1[1]*d11) * bsr[0];
                pB[ch][1][1][w] = ((float)iz1[0]*d10 + (float)iz1[1]*d11) * bsr[1];
                pB[ch][2][1][w] = ((float)in1[0]*d10 + (float)in1[1]*d11) * bsr[2];
            }
            __syncthreads();  // B3

            // ---- Gates + h update + FC partials (thread role: (b=ch, w)) ----
            {
                float GR = pB[0][0][ch][w] + pB[1][0][ch][w];
                float GZ = pB[0][1][ch][w] + pB[1][1][ch][w];
                float GN = pB[0][2][ch][w] + pB[1][2][ch][w];
                float xl = (t == 0) ? 0.f : sx[ch][(i << 4) + col - dir];
                float xu = (i == 0) ? 0.f : sx[ch][((i - 1) << 4) + col];
                float pu = (xl * xc0 + xu * xc1 + 1.f) * 0.5f;
                float rr = fsig(bA[0] * pu + bBi[0] + GR + bbh[0]);
                float zz = fsig(bA[1] * pu + bBi[1] + GZ + bbh[1]);
                float nn = ftanh_(bA[2] * pu + bBi[2] + rr * (GN + bbh[2]));
                float hn = (1.f - zz) * nn + zz * hi_f;

                unsigned hu = (unsigned)f16b(hn);
                unsigned hnx = __shfl_down(hu, 1);
                unsigned pk = hu | (hnx << 16);
                if ((w & 1) == 0) {
                    h2pk[ch][w >> 1] = pk;
                    hp2pk[ch][col][w >> 1] = pk;
                }
                float s0 = hn * wfc0, s1 = hn * wfc1;
                #pragma unroll
                for (int o = 1; o < 64; o <<= 1) {
                    s0 += __shfl_xor(s0, o);
                    s1 += __shfl_xor(s1, o);
                }
                if ((w & 63) == 0) {
                    fcp[ch][0][w >> 6] = s0;
                    fcp[ch][1][w >> 6] = s1;
                }
            }
            __syncthreads();  // B4 (protects h/fcp for next step's Phase A / finalize)
        }
    }

    // ---- final step's FC finalize + output ----
    if (w == 0) {
        float l0 = fcp[ch][0][0] + fcp[ch][0][1] + fcp[ch][0][2] + fcp[ch][0][3] + bf0;
        float l1 = fcp[ch][1][0] + fcp[ch][1][1] + fcp[ch][1][2] + fcp[ch][1][3] + bf1;
        float mx = fmaxf(l0, l1);
        float lse = mx + logf(__expf(l0 - mx) + __expf(l1 - mx));
        float xcur = sx[ch][15 * 16 + 0];   // last step: i=15 (odd), col=0
        float mm = (1.f + xcur) * 0.5f;
        lp_acc += (l0 - lse) * mm + (l1 - lse) * (1.f - mm);
        out[b0 + ch] = lp_acc;
    }
}

extern "C" void kernel_launch(void* const* d_in, const int* in_sizes, int n_in,
                              void* d_out, int out_size, void* d_ws, size_t ws_size,
                              hipStream_t stream) {
    const float* x      = (const float*)d_in[0];
    const float* W_ih   = (const float*)d_in[1];
    const float* W_hh   = (const float*)d_in[2];
    const float* b_ih   = (const float*)d_in[3];
    const float* b_hh   = (const float*)d_in[4];
    const float* W_fc   = (const float*)d_in[5];
    const float* b_fc   = (const float*)d_in[6];
    const float* W_hcat = (const float*)d_in[7];
    const float* W_xcat = (const float*)d_in[8];
    float* out = (float*)d_out;
    float* ws  = (float*)d_ws;

    gru2d_prep1<<<768, 64, 0, stream>>>(W_hh, ws);
    gru2d_prep2<<<451, 256, 0, stream>>>(W_ih, W_hh, b_ih, W_hcat, ws);
    gru2d_main<<<256, 512, 0, stream>>>(x, b_hh, W_fc, b_fc, W_xcat, ws, out);
}